// Round 1
// baseline (1109.733 us; speedup 1.0000x reference)
//
#include <hip/hip_runtime.h>
#include <cstddef>

#define NT   256   // threads per block = number of gates
#define BPB  4     // batch rows per block
#define HDIM 64
#define TMAX 512

__device__ __forceinline__ float fsig(float x) {
    x = fminf(fmaxf(x, -30.f), 30.f);
    float e = __expf(-x);
    return __builtin_amdgcn_rcpf(1.f + e);
}
__device__ __forceinline__ float ftanh(float x) {
    x = fminf(fmaxf(x, -15.f), 15.f);      // tanh(15) == 1.0f in fp32; avoids inf/inf
    float e = __expf(2.f * x);
    return (e - 1.f) * __builtin_amdgcn_rcpf(e + 1.f);
}

__global__ __launch_bounds__(NT, 2)
void lstm_seq_kernel(const float* __restrict__ ctx_g,   // (B, T)
                     const float* __restrict__ Wih_e,   // (256,1)
                     const float* __restrict__ Whh_e,   // (256,64)
                     const float* __restrict__ bih_e,
                     const float* __restrict__ bhh_e,
                     const float* __restrict__ Wih_d,
                     const float* __restrict__ Whh_d,
                     const float* __restrict__ bih_d,
                     const float* __restrict__ bhh_d,
                     const float* __restrict__ Whead,   // (1,64)
                     const float* __restrict__ bhead,   // (1,)
                     float* __restrict__ out,           // (B, n_steps)
                     int T, int n_steps)
{
    __shared__ __align__(16) float ctx[BPB][TMAX];
    __shared__ __align__(16) float h_lds[BPB][HDIM];
    __shared__ float act[BPB][NT];
    __shared__ float z_lds[BPB];

    const int tid = threadIdx.x;
    const int j   = tid;        // gate index this thread owns
    const int u   = tid & 63;   // hidden unit for the update role
    const int m   = tid >> 6;   // batch slot for the update role (wave == batch)
    const size_t b0 = (size_t)blockIdx.x * BPB;

    // stage context rows into LDS (coalesced)
    for (int mm = 0; mm < BPB; ++mm)
        for (int t = tid; t < T; t += NT)
            ctx[mm][t] = ctx_g[(b0 + mm) * (size_t)T + t];

    // encoder weights: W_hh row in registers
    float w[HDIM];
    {
        const float4* wr = reinterpret_cast<const float4*>(Whh_e + (size_t)j * HDIM);
        #pragma unroll
        for (int k4 = 0; k4 < HDIM / 4; ++k4) {
            float4 wv = wr[k4];
            w[4*k4+0] = wv.x; w[4*k4+1] = wv.y; w[4*k4+2] = wv.z; w[4*k4+3] = wv.w;
        }
    }
    float wih  = Wih_e[j];
    float bias = bih_e[j] + bhh_e[j];

    float c_reg = 0.f;          // cell state for (u, m) — stays in a register
    h_lds[m][u] = 0.f;          // 256 threads cover BPB*64 exactly
    __syncthreads();

    const bool is_g = (j >= 128) && (j < 192);   // wave-uniform (wave 2)

    // ---------------- encoder: T sequential steps ----------------
    for (int t = 0; t < T; ++t) {
        float acc[BPB];
        #pragma unroll
        for (int mm = 0; mm < BPB; ++mm)
            acc[mm] = fmaf(ctx[mm][t], wih, bias);
        #pragma unroll
        for (int k4 = 0; k4 < HDIM / 4; ++k4) {
            #pragma unroll
            for (int mm = 0; mm < BPB; ++mm) {
                float4 hv = *reinterpret_cast<const float4*>(&h_lds[mm][4 * k4]);
                acc[mm] = fmaf(hv.x, w[4*k4+0], acc[mm]);
                acc[mm] = fmaf(hv.y, w[4*k4+1], acc[mm]);
                acc[mm] = fmaf(hv.z, w[4*k4+2], acc[mm]);
                acc[mm] = fmaf(hv.w, w[4*k4+3], acc[mm]);
            }
        }
        if (is_g) {
            #pragma unroll
            for (int mm = 0; mm < BPB; ++mm) act[mm][j] = ftanh(acc[mm]);
        } else {
            #pragma unroll
            for (int mm = 0; mm < BPB; ++mm) act[mm][j] = fsig(acc[mm]);
        }
        __syncthreads();
        float ig = act[m][u];
        float fg = act[m][u + 64];
        float gg = act[m][u + 128];
        float og = act[m][u + 192];
        float cn = fmaf(fg, c_reg, ig * gg);
        c_reg = cn;
        h_lds[m][u] = og * ftanh(cn);
        __syncthreads();
    }

    // ---------------- decoder weights ----------------
    {
        const float4* wr = reinterpret_cast<const float4*>(Whh_d + (size_t)j * HDIM);
        #pragma unroll
        for (int k4 = 0; k4 < HDIM / 4; ++k4) {
            float4 wv = wr[k4];
            w[4*k4+0] = wv.x; w[4*k4+1] = wv.y; w[4*k4+2] = wv.z; w[4*k4+3] = wv.w;
        }
    }
    wih  = Wih_d[j];
    bias = bih_d[j] + bhh_d[j];
    const float whead = Whead[u];
    const float bh    = bhead[0];

    if (tid < BPB) z_lds[tid] = ctx[tid][T - 1];
    __syncthreads();

    // ---------------- decoder: n_steps sequential steps ----------------
    for (int s = 0; s < n_steps; ++s) {
        float acc[BPB];
        #pragma unroll
        for (int mm = 0; mm < BPB; ++mm)
            acc[mm] = fmaf(z_lds[mm], wih, bias);
        #pragma unroll
        for (int k4 = 0; k4 < HDIM / 4; ++k4) {
            #pragma unroll
            for (int mm = 0; mm < BPB; ++mm) {
                float4 hv = *reinterpret_cast<const float4*>(&h_lds[mm][4 * k4]);
                acc[mm] = fmaf(hv.x, w[4*k4+0], acc[mm]);
                acc[mm] = fmaf(hv.y, w[4*k4+1], acc[mm]);
                acc[mm] = fmaf(hv.z, w[4*k4+2], acc[mm]);
                acc[mm] = fmaf(hv.w, w[4*k4+3], acc[mm]);
            }
        }
        if (is_g) {
            #pragma unroll
            for (int mm = 0; mm < BPB; ++mm) act[mm][j] = ftanh(acc[mm]);
        } else {
            #pragma unroll
            for (int mm = 0; mm < BPB; ++mm) act[mm][j] = fsig(acc[mm]);
        }
        __syncthreads();
        float ig = act[m][u];
        float fg = act[m][u + 64];
        float gg = act[m][u + 128];
        float og = act[m][u + 192];
        float cn = fmaf(fg, c_reg, ig * gg);
        c_reg = cn;
        float hn = og * ftanh(cn);
        h_lds[m][u] = hn;

        // head: z_next[m] = sum_u hn * Whead[u] + b_head   (64-lane reduce per wave)
        float p = hn * whead;
        #pragma unroll
        for (int off = 32; off >= 1; off >>= 1)
            p += __shfl_xor(p, off);
        if (u == 0) {
            float zn = p + bh;
            z_lds[m] = zn;
            out[(b0 + m) * (size_t)n_steps + s] = zn;
        }
        __syncthreads();
    }
}

extern "C" void kernel_launch(void* const* d_in, const int* in_sizes, int n_in,
                              void* d_out, int out_size, void* d_ws, size_t ws_size,
                              hipStream_t stream)
{
    const float* ctx   = (const float*)d_in[0];
    const float* Wih_e = (const float*)d_in[1];
    const float* Whh_e = (const float*)d_in[2];
    const float* bih_e = (const float*)d_in[3];
    const float* bhh_e = (const float*)d_in[4];
    const float* Wih_d = (const float*)d_in[5];
    const float* Whh_d = (const float*)d_in[6];
    const float* bih_d = (const float*)d_in[7];
    const float* bhh_d = (const float*)d_in[8];
    const float* Whead = (const float*)d_in[9];
    const float* bhead = (const float*)d_in[10];
    float* out = (float*)d_out;

    const int B = 2048;                 // fixed by the harness setup
    const int T = in_sizes[0] / B;      // 512
    const int n_steps = out_size / B;   // 256

    lstm_seq_kernel<<<dim3(B / BPB), dim3(NT), 0, stream>>>(
        ctx, Wih_e, Whh_e, bih_e, bhh_e,
        Wih_d, Whh_d, bih_d, bhh_d,
        Whead, bhead, out, T, n_steps);
}

// Round 2
// 600.255 us; speedup vs baseline: 1.8488x; 1.8488x over previous
//
#include <hip/hip_runtime.h>
#include <cstddef>
#include <cstdint>

#define TMAX 512
#define HDIM 64

typedef _Float16 half2v __attribute__((ext_vector_type(2)));

__device__ __forceinline__ float fsig(float x) {
    x = fminf(fmaxf(x, -30.f), 30.f);
    float e = __expf(-x);
    return __builtin_amdgcn_rcpf(1.f + e);
}
__device__ __forceinline__ float ftanh(float x) {
    x = fminf(fmaxf(x, -15.f), 15.f);      // tanh(15)==1 in fp32; avoid inf/inf
    float e = __expf(2.f * x);
    return (e - 1.f) * __builtin_amdgcn_rcpf(e + 1.f);
}

#if __has_builtin(__builtin_amdgcn_fdot2)
__device__ __forceinline__ float dot2acc(half2v a, half2v b, float c) {
    return __builtin_amdgcn_fdot2(a, b, c, false);   // v_dot2_f32_f16
}
#else
__device__ __forceinline__ float dot2acc(half2v a, half2v b, float c) {
    return fmaf((float)a.y, (float)b.y, fmaf((float)a.x, (float)b.x, c));
}
#endif

// One wave (64 lanes) per batch row. Lane u owns hidden unit u and computes
// gates u, u+64, u+128, u+192. No __syncthreads anywhere: h is exchanged
// within the wave through a 128-byte LDS buffer (uniform-address broadcast
// reads; wave-internal LDS ordering is guaranteed by lgkmcnt).
__global__ __launch_bounds__(64, 2)
void lstm_wave_kernel(const float* __restrict__ ctx_g,   // (B, T)
                      const float* __restrict__ Wih_e,   // (256,1)
                      const float* __restrict__ Whh_e,   // (256,64)
                      const float* __restrict__ bih_e,
                      const float* __restrict__ bhh_e,
                      const float* __restrict__ Wih_d,
                      const float* __restrict__ Whh_d,
                      const float* __restrict__ bih_d,
                      const float* __restrict__ bhh_d,
                      const float* __restrict__ Whead,   // (1,64)
                      const float* __restrict__ bhead,   // (1,)
                      float* __restrict__ out,           // (B, n_steps)
                      int T, int n_steps)
{
    __shared__ __align__(16) float    ctx_s[TMAX];
    __shared__ __align__(16) _Float16 h_s[HDIM];

    const int lane = threadIdx.x;           // 0..63 == hidden unit
    const int row  = blockIdx.x;            // batch row

    // stage this row's context (coalesced within the wave)
    const float* ctxr = ctx_g + (size_t)row * T;
    for (int t = lane; t < T; t += 64) ctx_s[t] = ctxr[t];

    // ---- encoder weights into registers (fp16-packed pairs) ----
    half2v w2[4][32];                        // 128 VGPRs
    float  wih[4], bias[4];
    #pragma unroll
    for (int g = 0; g < 4; ++g) {
        const int j = lane + (g << 6);
        const float2* wr = reinterpret_cast<const float2*>(Whh_e + (size_t)j * HDIM);
        #pragma unroll
        for (int k = 0; k < 32; ++k) {
            float2 wv = wr[k];
            w2[g][k] = half2v{(_Float16)wv.x, (_Float16)wv.y};
        }
        wih[g]  = Wih_e[j];
        bias[g] = bih_e[j] + bhh_e[j];
    }

    float c = 0.f, h = 0.f;
    h_s[lane] = (_Float16)0.f;

    // ---------------- encoder: T sequential steps ----------------
    for (int t = 0; t < T; ++t) {
        const float x = ctx_s[t];
        float a0 = fmaf(x, wih[0], bias[0]);
        float a1 = fmaf(x, wih[1], bias[1]);
        float a2 = fmaf(x, wih[2], bias[2]);
        float a3 = fmaf(x, wih[3], bias[3]);
        #pragma unroll
        for (int ch = 0; ch < 8; ++ch) {     // 8 x ds_read_b128 (broadcast)
            half2v hp[4];
            *reinterpret_cast<uint4*>(hp) =
                reinterpret_cast<const uint4*>(h_s)[ch];
            #pragma unroll
            for (int e = 0; e < 4; ++e) {
                const int k = ch * 4 + e;
                a0 = dot2acc(w2[0][k], hp[e], a0);
                a1 = dot2acc(w2[1][k], hp[e], a1);
                a2 = dot2acc(w2[2][k], hp[e], a2);
                a3 = dot2acc(w2[3][k], hp[e], a3);
            }
        }
        const float ig = fsig(a0);
        const float fg = fsig(a1);
        const float gg = ftanh(a2);
        const float og = fsig(a3);
        c = fmaf(fg, c, ig * gg);
        h = og * ftanh(c);
        h_s[lane] = (_Float16)h;             // visible to the wave next step
    }

    // ---------------- decoder weights ----------------
    #pragma unroll
    for (int g = 0; g < 4; ++g) {
        const int j = lane + (g << 6);
        const float2* wr = reinterpret_cast<const float2*>(Whh_d + (size_t)j * HDIM);
        #pragma unroll
        for (int k = 0; k < 32; ++k) {
            float2 wv = wr[k];
            w2[g][k] = half2v{(_Float16)wv.x, (_Float16)wv.y};
        }
        wih[g]  = Wih_d[j];
        bias[g] = bih_d[j] + bhh_d[j];
    }
    const float wh = Whead[lane];
    const float bh = bhead[0];
    float z = ctx_s[T - 1];                  // z0 = context[:, -1]

    // ---------------- decoder: n_steps sequential steps ----------------
    for (int s = 0; s < n_steps; ++s) {
        float a0 = fmaf(z, wih[0], bias[0]);
        float a1 = fmaf(z, wih[1], bias[1]);
        float a2 = fmaf(z, wih[2], bias[2]);
        float a3 = fmaf(z, wih[3], bias[3]);
        #pragma unroll
        for (int ch = 0; ch < 8; ++ch) {
            half2v hp[4];
            *reinterpret_cast<uint4*>(hp) =
                reinterpret_cast<const uint4*>(h_s)[ch];
            #pragma unroll
            for (int e = 0; e < 4; ++e) {
                const int k = ch * 4 + e;
                a0 = dot2acc(w2[0][k], hp[e], a0);
                a1 = dot2acc(w2[1][k], hp[e], a1);
                a2 = dot2acc(w2[2][k], hp[e], a2);
                a3 = dot2acc(w2[3][k], hp[e], a3);
            }
        }
        const float ig = fsig(a0);
        const float fg = fsig(a1);
        const float gg = ftanh(a2);
        const float og = fsig(a3);
        c = fmaf(fg, c, ig * gg);
        h = og * ftanh(c);
        h_s[lane] = (_Float16)h;

        // head: z = sum_u h[u]*Whead[u] + b  (fp32 butterfly; all lanes get
        // the identical value, so z stays wave-uniform for the next step)
        float p = h * wh;
        #pragma unroll
        for (int off = 32; off >= 1; off >>= 1)
            p += __shfl_xor(p, off);
        z = p + bh;
        if (lane == 0) out[(size_t)row * n_steps + s] = z;
    }
}

extern "C" void kernel_launch(void* const* d_in, const int* in_sizes, int n_in,
                              void* d_out, int out_size, void* d_ws, size_t ws_size,
                              hipStream_t stream)
{
    const float* ctx   = (const float*)d_in[0];
    const float* Wih_e = (const float*)d_in[1];
    const float* Whh_e = (const float*)d_in[2];
    const float* bih_e = (const float*)d_in[3];
    const float* bhh_e = (const float*)d_in[4];
    const float* Wih_d = (const float*)d_in[5];
    const float* Whh_d = (const float*)d_in[6];
    const float* bih_d = (const float*)d_in[7];
    const float* bhh_d = (const float*)d_in[8];
    const float* Whead = (const float*)d_in[9];
    const float* bhead = (const float*)d_in[10];
    float* out = (float*)d_out;

    const int B = 2048;                 // fixed by the harness setup
    const int T = in_sizes[0] / B;      // 512
    const int n_steps = out_size / B;   // 256

    lstm_wave_kernel<<<dim3(B), dim3(64), 0, stream>>>(
        ctx, Wih_e, Whh_e, bih_e, bhh_e,
        Wih_d, Whh_d, bih_d, bhh_d,
        Whead, bhead, out, T, n_steps);
}